// Round 1
// baseline (92249.408 us; speedup 1.0000x reference)
//
#include <hip/hip_runtime.h>
#include <hip/hip_cooperative_groups.h>
#include <math.h>

namespace cg = cooperative_groups;

#define NB 4
#define NS 512
#define ND 512
#define NH 8
#define NHD 64
#define NL 2
#define NFF 2048
#define NV 32000
#define ATT_SCALE 0.125f
#define EMB_SCALEF 22.627416997969522f

struct P {
  const int* ids;
  const float *tok, *pos, *lw, *kW, *kb, *vW, *vb, *qW, *qb, *oW, *ob;
  const float *f1W, *f1b, *f2W, *f2b, *ln1w, *ln1b, *ln2w, *ln2b, *lnfw, *lnfb, *headW;
  float *emb, *memk, *memv, *hidden, *q, *att, *r1, *r2, *ff1, *kv0k, *kv0v;
};

// ---- block-wide (256-thread) reductions; red must be float[4] shared ----
__device__ __forceinline__ float blk_sum(float v, float* red) {
  #pragma unroll
  for (int o = 32; o > 0; o >>= 1) v += __shfl_down(v, o, 64);
  const int tid = threadIdx.x;
  __syncthreads();
  if ((tid & 63) == 0) red[tid >> 6] = v;
  __syncthreads();
  return red[0] + red[1] + red[2] + red[3];
}

__device__ __forceinline__ float blk_max(float v, float* red) {
  #pragma unroll
  for (int o = 32; o > 0; o >>= 1) v = fmaxf(v, __shfl_down(v, o, 64));
  const int tid = threadIdx.x;
  __syncthreads();
  if ((tid & 63) == 0) red[tid >> 6] = v;
  __syncthreads();
  return fmaxf(fmaxf(red[0], red[1]), fmaxf(red[2], red[3]));
}

__device__ __forceinline__ void ln_stats(const float* __restrict__ v, float& mean, float& rstd, float* red) {
  const int tid = threadIdx.x;
  float s = 0.f, q = 0.f;
  for (int i = tid; i < ND; i += 256) { float x = v[i]; s += x; q += x * x; }
  s = blk_sum(s, red);
  q = blk_sum(q, red);
  mean = s * (1.0f / ND);
  rstd = rsqrtf(q * (1.0f / ND) - mean * mean + 1e-5f);
}

// Persistent cooperative scan kernel: 64 WGs x 256 threads.
// WG w -> batch b = w>>4, slice sl = w&15 (slice s of all batches shares XCD s%8).
__global__ void __launch_bounds__(256) scan_kernel(P p) {
  cg::grid_group grid = cg::this_grid();
  const int wg = blockIdx.x;
  const int b = wg >> 4;
  const int sl = wg & 15;
  const int tid = threadIdx.x;

  __shared__ float xs[2048];
  __shared__ float part[256];
  __shared__ float red[4];

  // ---- embedding: emb[b,t,d] = tok[ids]*scale + pos[t,d] ----
  for (int i = wg * 256 + tid; i < NB * NS * ND; i += 64 * 256) {
    int d = i & (ND - 1);
    int bs = i >> 9;
    int t = bs & (NS - 1);
    int bb = bs >> 9;
    p.emb[i] = p.tok[(size_t)p.ids[bb * NS + t] * ND + d] * EMB_SCALEF + p.pos[t * ND + d];
  }
  grid.sync();

  // ---- kv0 = emb[:,0] @ {kW,vW} + {kb,vb} ----
  {
    for (int i = tid; i < ND; i += 256) xs[i] = p.emb[(size_t)b * NS * ND + i];
    __syncthreads();
    int oid = tid & 63, chunk = tid >> 6;            // 64 outs, 4 chunks of 128
    bool isv = oid >= 32;
    int j = sl * 32 + (oid & 31);
    const float* W = isv ? p.vW : p.kW;
    const float* wp = W + (size_t)(chunk * 128) * ND + j;
    float acc = 0.f;
    #pragma unroll 4
    for (int d = 0; d < 128; d++) acc = fmaf(xs[chunk * 128 + d], wp[(size_t)d * ND], acc);
    part[tid] = acc;
    __syncthreads();
    if (tid < 64) {
      float r = part[tid] + part[64 + tid] + part[128 + tid] + part[192 + tid];
      bool iv = tid >= 32;
      int jj = sl * 32 + (tid & 31);
      if (!iv) p.kv0k[b * ND + jj] = r + p.kb[jj];
      else     p.kv0v[b * ND + jj] = r + p.vb[jj];
    }
  }
  grid.sync();

  // softmax of layer weights (3 scalars, computed redundantly)
  float w0, w1, w2;
  {
    float a0 = p.lw[0], a1 = p.lw[1], a2 = p.lw[2];
    float mx = fmaxf(a0, fmaxf(a1, a2));
    float e0 = expf(a0 - mx), e1 = expf(a1 - mx), e2 = expf(a2 - mx);
    float inv = 1.f / (e0 + e1 + e2);
    w0 = e0 * inv; w1 = e1 * inv; w2 = e2 * inv;
  }

  for (int t = 0; t < NS; t++) {
    const float* xin0 = p.emb + ((size_t)b * NS + t) * ND;
    const int len = (t == 0) ? 1 : t;

    for (int l = 0; l < NL; l++) {
      // ---- PA: q = x @ qW[l] + qb[l] ----
      if (l == 0) {
        for (int i = tid; i < ND; i += 256) xs[i] = xin0[i];
        __syncthreads();
      } else {
        const float* rv = p.r2 + (size_t)b * ND;   // layer0 pre-LN output
        float mean, rstd;
        ln_stats(rv, mean, rstd, red);
        for (int i = tid; i < ND; i += 256)
          xs[i] = (rv[i] - mean) * rstd * p.ln2w[i] + p.ln2b[i];
        __syncthreads();
      }
      {
        int jl = tid & 31, chunk = tid >> 5;        // 32 outs, 8 chunks of 64
        int j = sl * 32 + jl;
        const float* wp = p.qW + (size_t)l * ND * ND + (size_t)(chunk * 64) * ND + j;
        float acc = 0.f;
        #pragma unroll 4
        for (int d = 0; d < 64; d++) acc = fmaf(xs[chunk * 64 + d], wp[(size_t)d * ND], acc);
        part[tid] = acc;
        __syncthreads();
        if (tid < 32) {
          float r = 0.f;
          #pragma unroll
          for (int c = 0; c < 8; c++) r += part[c * 32 + tid];
          int j2 = sl * 32 + tid;
          p.q[b * ND + j2] = r + p.qb[l * ND + j2];
        }
      }
      grid.sync();

      // ---- PB: attention per (b,h); WGs 0..31 active ----
      if (wg < 32) {
        int ab = wg >> 3, ah = wg & 7;
        const float* kp = (t == 0) ? (p.kv0k + ab * ND) : (p.memk + (size_t)ab * NS * ND);
        const float* vp = (t == 0) ? (p.kv0v + ab * ND) : (p.memv + (size_t)ab * NS * ND);
        if (tid < 64) xs[512 + tid] = p.q[ab * ND + ah * NHD + tid];
        __syncthreads();
        float lmax = -1e30f;
        for (int m = tid; m < len; m += 256) {
          const float* kr = kp + (size_t)m * ND + ah * NHD;
          float acc = 0.f;
          #pragma unroll
          for (int i = 0; i < NHD; i++) acc = fmaf(xs[512 + i], kr[i], acc);
          float sv = acc * ATT_SCALE;
          xs[m] = sv;
          lmax = fmaxf(lmax, sv);
        }
        lmax = blk_max(lmax, red);
        float lsum = 0.f;
        for (int m = tid; m < len; m += 256) { float e = expf(xs[m] - lmax); xs[m] = e; lsum += e; }
        lsum = blk_sum(lsum, red);
        float inv = 1.f / lsum;
        int hd = tid & 63, ch = tid >> 6;
        float acc = 0.f;
        for (int m = ch; m < len; m += 4) acc = fmaf(xs[m], vp[(size_t)m * ND + ah * NHD + hd], acc);
        part[tid] = acc;
        __syncthreads();
        if (tid < 64) {
          float r = (part[tid] + part[64 + tid] + part[128 + tid] + part[192 + tid]) * inv;
          p.att[ab * ND + ah * NHD + tid] = r;
        }
      }
      grid.sync();

      // ---- PC: o = att @ oW[l] + ob[l]; r1 = x_in + o (pre-LN stored) ----
      {
        for (int i = tid; i < ND; i += 256) xs[i] = p.att[b * ND + i];
        float mean = 0.f, rstd = 0.f;
        if (l == 1) {
          const float* rv = p.r2 + (size_t)b * ND;
          ln_stats(rv, mean, rstd, red);
        }
        __syncthreads();
        int jl = tid & 31, chunk = tid >> 5;
        int j = sl * 32 + jl;
        const float* wp = p.oW + (size_t)l * ND * ND + (size_t)(chunk * 64) * ND + j;
        float acc = 0.f;
        #pragma unroll 4
        for (int d = 0; d < 64; d++) acc = fmaf(xs[chunk * 64 + d], wp[(size_t)d * ND], acc);
        part[tid] = acc;
        __syncthreads();
        if (tid < 32) {
          float r = 0.f;
          #pragma unroll
          for (int c = 0; c < 8; c++) r += part[c * 32 + tid];
          int j2 = sl * 32 + tid;
          float xinv;
          if (l == 0) xinv = xin0[j2];
          else {
            const float* rv = p.r2 + (size_t)b * ND;
            xinv = (rv[j2] - mean) * rstd * p.ln2w[j2] + p.ln2b[j2];
          }
          p.r1[b * ND + j2] = xinv + r + p.ob[l * ND + j2];
        }
      }
      grid.sync();

      // ---- PD: ff1 = relu(ln1(r1) @ f1W[l] + f1b[l]) ----
      {
        const float* rv = p.r1 + b * ND;
        float mean, rstd;
        ln_stats(rv, mean, rstd, red);
        for (int i = tid; i < ND; i += 256)
          xs[i] = (rv[i] - mean) * rstd * p.ln1w[l * ND + i] + p.ln1b[l * ND + i];
        __syncthreads();
        int jl = tid & 127, chunk = tid >> 7;      // 128 outs, 2 chunks of 256
        int j = sl * 128 + jl;
        const float* wp = p.f1W + (size_t)l * ND * NFF + (size_t)(chunk * 256) * NFF + j;
        float acc = 0.f;
        #pragma unroll 4
        for (int d = 0; d < 256; d++) acc = fmaf(xs[chunk * 256 + d], wp[(size_t)d * NFF], acc);
        part[tid] = acc;
        __syncthreads();
        if (tid < 128) {
          float r = part[tid] + part[128 + tid] + p.f1b[l * NFF + sl * 128 + tid];
          p.ff1[b * NFF + sl * 128 + tid] = fmaxf(r, 0.f);
        }
      }
      grid.sync();

      // ---- PE: r2[l] = ln1(r1) + ff1 @ f2W[l] + f2b[l]  (pre-LN stored) ----
      {
        for (int i = tid; i < NFF; i += 256) xs[i] = p.ff1[b * NFF + i];
        const float* rv = p.r1 + b * ND;
        float mean, rstd;
        ln_stats(rv, mean, rstd, red);
        __syncthreads();
        int jl = tid & 31, chunk = tid >> 5;       // 32 outs, 8 chunks of 256
        int j = sl * 32 + jl;
        const float* wp = p.f2W + (size_t)l * NFF * ND + (size_t)(chunk * 256) * ND + j;
        float acc = 0.f;
        #pragma unroll 4
        for (int d = 0; d < 256; d++) acc = fmaf(xs[chunk * 256 + d], wp[(size_t)d * ND], acc);
        part[tid] = acc;
        __syncthreads();
        if (tid < 32) {
          float r = 0.f;
          #pragma unroll
          for (int c = 0; c < 8; c++) r += part[c * 32 + tid];
          int j2 = sl * 32 + tid;
          float x1 = (rv[j2] - mean) * rstd * p.ln1w[l * ND + j2] + p.ln1b[l * ND + j2];
          p.r2[((size_t)l * NB + b) * ND + j2] = x1 + r + p.f2b[l * ND + j2];
        }
      }
      grid.sync();
    } // layers

    // ---- PM: m = w0*emb + w1*ln2_0(r2_0) + w2*ln2_1(r2_1); mem[t] = m@{kW,vW}+{kb,vb}; hidden[t]=ln2_1 ----
    {
      const float* r20 = p.r2 + (size_t)b * ND;
      const float* r21 = p.r2 + ((size_t)NB + b) * ND;
      float m0, s0, m1, s1;
      ln_stats(r20, m0, s0, red);
      ln_stats(r21, m1, s1, red);
      for (int i = tid; i < ND; i += 256) {
        float x2 = (r20[i] - m0) * s0 * p.ln2w[i] + p.ln2b[i];
        float x4 = (r21[i] - m1) * s1 * p.ln2w[ND + i] + p.ln2b[ND + i];
        xs[i] = w0 * xin0[i] + w1 * x2 + w2 * x4;
        if (sl == 0) p.hidden[((size_t)b * NS + t) * ND + i] = x4;
      }
      __syncthreads();
      int oid = tid & 63, chunk = tid >> 6;
      bool isv = oid >= 32;
      int j = sl * 32 + (oid & 31);
      const float* W = isv ? p.vW : p.kW;
      const float* wp = W + (size_t)(chunk * 128) * ND + j;
      float acc = 0.f;
      #pragma unroll 4
      for (int d = 0; d < 128; d++) acc = fmaf(xs[chunk * 128 + d], wp[(size_t)d * ND], acc);
      part[tid] = acc;
      __syncthreads();
      if (tid < 64) {
        float r = part[tid] + part[64 + tid] + part[128 + tid] + part[192 + tid];
        bool iv = tid >= 32;
        int jj = sl * 32 + (tid & 31);
        if (!iv) p.memk[((size_t)b * NS + t) * ND + jj] = r + p.kb[jj];
        else     p.memv[((size_t)b * NS + t) * ND + jj] = r + p.vb[jj];
      }
    }
    grid.sync();
  } // t
}

// ---- final layernorm over hidden rows ----
__global__ void __launch_bounds__(256) lnf_kernel(const float* __restrict__ hidden,
                                                  const float* __restrict__ w,
                                                  const float* __restrict__ bi,
                                                  float* __restrict__ out) {
  __shared__ float red[4];
  const int row = blockIdx.x;
  const float* x = hidden + (size_t)row * ND;
  float mean, rstd;
  ln_stats(x, mean, rstd, red);
  for (int i = threadIdx.x; i < ND; i += 256)
    out[(size_t)row * ND + i] = (x[i] - mean) * rstd * w[i] + bi[i];
}

// ---- head GEMM: C[2048,32000] = A[2048,512] @ W[512,32000], fp32 ----
__global__ void __launch_bounds__(256) head_gemm(const float* __restrict__ A,
                                                 const float* __restrict__ Bw,
                                                 float* __restrict__ C) {
  __shared__ float As[8][128];
  __shared__ float Bs[8][128];
  const int tid = threadIdx.x;
  const int col0 = blockIdx.x * 128;
  const int row0 = blockIdx.y * 128;
  const int tx = tid & 15, ty = tid >> 4;
  float acc[8][8] = {};

  for (int k0 = 0; k0 < 512; k0 += 8) {
    {
      int r = tid >> 1, kk = (tid & 1) * 4;
      const float4 v = *(const float4*)(A + (size_t)(row0 + r) * 512 + k0 + kk);
      As[kk + 0][r] = v.x; As[kk + 1][r] = v.y; As[kk + 2][r] = v.z; As[kk + 3][r] = v.w;
      int brr = tid >> 5, bcc = (tid & 31) * 4;
      *(float4*)&Bs[brr][bcc] = *(const float4*)(Bw + (size_t)(k0 + brr) * NV + col0 + bcc);
    }
    __syncthreads();
    #pragma unroll
    for (int kk = 0; kk < 8; kk++) {
      float a[8], bv[8];
      #pragma unroll
      for (int i = 0; i < 8; i++) a[i] = As[kk][ty * 8 + i];
      #pragma unroll
      for (int j = 0; j < 8; j++) bv[j] = Bs[kk][tx * 8 + j];
      #pragma unroll
      for (int i = 0; i < 8; i++)
        #pragma unroll
        for (int j = 0; j < 8; j++) acc[i][j] = fmaf(a[i], bv[j], acc[i][j]);
    }
    __syncthreads();
  }
  #pragma unroll
  for (int i = 0; i < 8; i++) {
    float* cp = C + (size_t)(row0 + ty * 8 + i) * NV + col0 + tx * 8;
    float4 v0 = {acc[i][0], acc[i][1], acc[i][2], acc[i][3]};
    float4 v1 = {acc[i][4], acc[i][5], acc[i][6], acc[i][7]};
    *(float4*)cp = v0;
    *(float4*)(cp + 4) = v1;
  }
}

extern "C" void kernel_launch(void* const* d_in, const int* in_sizes, int n_in,
                              void* d_out, int out_size, void* d_ws, size_t ws_size,
                              hipStream_t stream) {
  P p;
  p.ids  = (const int*)d_in[0];
  p.tok  = (const float*)d_in[1];
  p.pos  = (const float*)d_in[2];
  p.lw   = (const float*)d_in[3];
  p.kW   = (const float*)d_in[4];
  p.kb   = (const float*)d_in[5];
  p.vW   = (const float*)d_in[6];
  p.vb   = (const float*)d_in[7];
  p.qW   = (const float*)d_in[8];
  p.qb   = (const float*)d_in[9];
  p.oW   = (const float*)d_in[10];
  p.ob   = (const float*)d_in[11];
  p.f1W  = (const float*)d_in[12];
  p.f1b  = (const float*)d_in[13];
  p.f2W  = (const float*)d_in[14];
  p.f2b  = (const float*)d_in[15];
  p.ln1w = (const float*)d_in[16];
  p.ln1b = (const float*)d_in[17];
  p.ln2w = (const float*)d_in[18];
  p.ln2b = (const float*)d_in[19];
  p.lnfw = (const float*)d_in[20];
  p.lnfb = (const float*)d_in[21];
  p.headW = (const float*)d_in[22];

  float* ws = (float*)d_ws;
  p.emb    = ws + 0;
  p.memk   = ws + 1048576;
  p.memv   = ws + 2097152;
  p.hidden = ws + 3145728;
  p.q      = ws + 4194304;
  p.att    = ws + 4196352;
  p.r1     = ws + 4198400;
  p.r2     = ws + 4200448;
  p.ff1    = ws + 4204544;
  p.kv0k   = ws + 4212736;
  p.kv0v   = ws + 4214784;

  void* args[] = { &p };
  hipLaunchCooperativeKernel((void*)scan_kernel, dim3(64), dim3(256), args, 0, stream);

  lnf_kernel<<<dim3(NB * NS), dim3(256), 0, stream>>>(p.hidden, p.lnfw, p.lnfb, p.emb);
  head_gemm<<<dim3(NV / 128, (NB * NS) / 128), dim3(256), 0, stream>>>(p.emb, p.headW, (float*)d_out);
}